// Round 2
// baseline (2878.765 us; speedup 1.0000x reference)
//
#include <hip/hip_runtime.h>
#include <hip/hip_bf16.h>

typedef unsigned short u16;
typedef unsigned int   u32;

#define Bsz 256
#define Tsz 256
#define Csz 384
#define Hn  6
#define Dh  64

__device__ __forceinline__ float bf2f(u16 u) {
    union { u32 i; float f; } x; x.i = ((u32)u) << 16; return x.f;
}
__device__ __forceinline__ u16 f2bf(float f) {
    union { u32 i; float f; } x; x.f = f;
    u32 r = x.i + 0x7FFFu + ((x.i >> 16) & 1u);   // RNE
    return (u16)(r >> 16);
}

// ---------------- QKV projection ----------------
// Inputs fp32. q,k,v written bf16, layout [B, H, T, D]. One block = 4 (b,t)
// rows; 384 threads: thread = (h,d) output column. x rows staged in LDS;
// 4-row reuse amortizes the 1.7MB fp32 weight stream through L2.
__global__ __launch_bounds__(384) void qkv_kernel(
    const float* __restrict__ x,  const float* __restrict__ Wq,
    const float* __restrict__ Wk, const float* __restrict__ Wv,
    u16* __restrict__ q, u16* __restrict__ k, u16* __restrict__ v)
{
    __shared__ float xrow[4][Csz];
    const int tid = threadIdx.x;
    const int bt0 = blockIdx.x * 4;
    #pragma unroll
    for (int r = 0; r < 4; ++r)
        xrow[r][tid] = x[(size_t)(bt0 + r) * Csz + tid];
    __syncthreads();

    const int h = tid >> 6, d = tid & 63;
    const float* wq = Wq + (size_t)h * Csz * Dh + d;
    const float* wk = Wk + (size_t)h * Csz * Dh + d;
    const float* wv = Wv + (size_t)h * Csz * Dh + d;
    float aq[4] = {0,0,0,0}, ak[4] = {0,0,0,0}, av[4] = {0,0,0,0};
    for (int c = 0; c < Csz; ++c) {
        float wqv = wq[c * Dh];
        float wkv = wk[c * Dh];
        float wvv = wv[c * Dh];
        #pragma unroll
        for (int r = 0; r < 4; ++r) {
            float xv = xrow[r][c];
            aq[r] += xv * wqv; ak[r] += xv * wkv; av[r] += xv * wvv;
        }
    }
    #pragma unroll
    for (int r = 0; r < 4; ++r) {
        int bt = bt0 + r, b = bt >> 8, t = bt & 255;
        size_t idx = (((size_t)(b * Hn + h)) * Tsz + t) * Dh + d;
        q[idx] = f2bf(aq[r]); k[idx] = f2bf(ak[r]); v[idx] = f2bf(av[r]);
    }
}

// ---------------- Causal attention ----------------
// One block (4 waves) per (b,h). q/k/v bf16 in ws. K staged transposed in
// LDS: Kt[d][s], row stride 260 ushorts -> conflict-free (consecutive s
// across lanes). Wave w owns query rows t = 4*j + w (balanced causal cost).
// V read from global: lanes read consecutive d -> 128B coalesced rows,
// L1-resident (32KB per head). att output layout [B,T,H*D] = [B,T,C] bf16.
__global__ __launch_bounds__(256) void attn_kernel(
    const u16* __restrict__ q, const u16* __restrict__ k, const u16* __restrict__ v,
    u16* __restrict__ att)
{
    __shared__ u16   Kt[Dh][Tsz + 4];
    __shared__ float sc[4][Tsz];
    __shared__ float qrow[4][Dh];
    const int bh = blockIdx.x;
    const int b = bh / Hn, h = bh % Hn;
    const int tid = threadIdx.x, w = tid >> 6, lane = tid & 63;
    const u16* qb = q + (size_t)bh * Tsz * Dh;
    const u16* kb = k + (size_t)bh * Tsz * Dh;
    const u16* vb = v + (size_t)bh * Tsz * Dh;

    for (int it = 0; it < 64; ++it) {
        int j = it * 256 + tid;          // j = s*64 + d
        Kt[j & 63][j >> 6] = kb[j];
    }
    __syncthreads();

    for (int jr = 0; jr < 64; ++jr) {
        const int t = jr * 4 + w;
        qrow[w][lane] = bf2f(qb[t * Dh + lane]);   // wave-internal, HW-ordered

        // scores: lane handles s = kk*64 + lane
        const int nk = (t >> 6) + 1;
        for (int kk = 0; kk < nk; ++kk) {
            const int s = kk * 64 + lane;
            float acc = 0.f;
            #pragma unroll 16
            for (int d = 0; d < Dh; ++d)
                acc += qrow[w][d] * bf2f(Kt[d][s]);
            if (s <= t) sc[w][s] = acc * 0.125f;   // 1/sqrt(64)
        }
        // softmax over s<=t
        float m = -3.4e38f;
        for (int kk = 0; kk < nk; ++kk) {
            int s = kk * 64 + lane;
            if (s <= t) m = fmaxf(m, sc[w][s]);
        }
        #pragma unroll
        for (int off = 32; off > 0; off >>= 1)
            m = fmaxf(m, __shfl_xor(m, off));
        float sum = 0.f;
        for (int kk = 0; kk < nk; ++kk) {
            int s = kk * 64 + lane;
            if (s <= t) { float e = __expf(sc[w][s] - m); sc[w][s] = e; sum += e; }
        }
        #pragma unroll
        for (int off = 32; off > 0; off >>= 1)
            sum += __shfl_xor(sum, off);
        const float inv = 1.f / sum;

        // PV: lane = d, broadcast sc[w][s], coalesced V row reads
        float acc = 0.f;
        #pragma unroll 4
        for (int s = 0; s <= t; ++s)
            acc += sc[w][s] * bf2f(vb[s * Dh + lane]);
        att[((size_t)(b * Tsz + t)) * Csz + h * Dh + lane] = f2bf(acc * inv);
    }
}

// ---------------- Output projection + bias ----------------
// att bf16 in ws, Wproj/bias fp32 inputs, out fp32.
__global__ __launch_bounds__(384) void proj_kernel(
    const u16* __restrict__ att, const float* __restrict__ Wp,
    const float* __restrict__ bias, float* __restrict__ out)
{
    __shared__ float arow[4][Csz];
    const int tid = threadIdx.x;
    const int bt0 = blockIdx.x * 4;
    #pragma unroll
    for (int r = 0; r < 4; ++r)
        arow[r][tid] = bf2f(att[(size_t)(bt0 + r) * Csz + tid]);
    __syncthreads();

    float a0 = bias[tid];
    float acc[4] = {a0, a0, a0, a0};
    for (int c = 0; c < Csz; ++c) {
        float wv = Wp[(size_t)c * Csz + tid];
        #pragma unroll
        for (int r = 0; r < 4; ++r)
            acc[r] += arow[r][c] * wv;
    }
    #pragma unroll
    for (int r = 0; r < 4; ++r)
        out[(size_t)(bt0 + r) * Csz + tid] = acc[r];
}

extern "C" void kernel_launch(void* const* d_in, const int* in_sizes, int n_in,
                              void* d_out, int out_size, void* d_ws, size_t ws_size,
                              hipStream_t stream)
{
    const float* x  = (const float*)d_in[0];
    const float* Wq = (const float*)d_in[1];
    const float* Wk = (const float*)d_in[2];
    const float* Wv = (const float*)d_in[3];
    const float* Wp = (const float*)d_in[4];
    const float* bp = (const float*)d_in[5];
    float* out = (float*)d_out;

    const size_t npe = (size_t)Bsz * Hn * Tsz * Dh;   // 25,165,824 elems
    u16* q   = (u16*)d_ws;        // [B,H,T,D] bf16
    u16* kk  = q  + npe;
    u16* v   = kk + npe;
    u16* att = v  + npe;          // [B,T,C]   bf16   (total ws: ~201 MB)

    qkv_kernel <<<Bsz * Tsz / 4, 384, 0, stream>>>(x, Wq, Wk, Wv, q, kk, v);
    attn_kernel<<<Bsz * Hn,      256, 0, stream>>>(q, kk, v, att);
    proj_kernel<<<Bsz * Tsz / 4, 384, 0, stream>>>(att, Wp, bp, out);
}

// Round 3
// 667.493 us; speedup vs baseline: 4.3128x; 4.3128x over previous
//
#include <hip/hip_runtime.h>
#include <hip/hip_bf16.h>

typedef __bf16 bf16;
typedef __attribute__((ext_vector_type(8))) __bf16 bf16x8;
typedef __attribute__((ext_vector_type(4))) float f32x4;

#define Bsz 256
#define Tsz 256
#define Csz 384
#define Hn  6
#define Dh  64

#define MFMA16(a, b, c) __builtin_amdgcn_mfma_f32_16x16x32_bf16(a, b, c, 0, 0, 0)

__device__ __forceinline__ float redmax16(float x) {
    x = fmaxf(x, __shfl_xor(x, 1));
    x = fmaxf(x, __shfl_xor(x, 2));
    x = fmaxf(x, __shfl_xor(x, 4));
    x = fmaxf(x, __shfl_xor(x, 8));
    return x;
}
__device__ __forceinline__ float redsum16(float x) {
    x += __shfl_xor(x, 1);
    x += __shfl_xor(x, 2);
    x += __shfl_xor(x, 4);
    x += __shfl_xor(x, 8);
    return x;
}

// ---------------- QKV projection, MFMA ----------------
// C[m,n] = x[m,:] . W[:,n].  Grid (1024, 18): y -> (which of q/k/v, head).
// Block tile 64(M)x64(N), K=384 in 6 chunks of 64. A staged [m][k] (fp32->bf16
// convert), B transpose-staged Bt[n][k] so B-frags are contiguous ds_read_b128.
// MFMA layouts (HW-verified): A m=lane&15,k=quad*8+j; C/D col=lane&15,row=quad*4+reg.
__global__ __launch_bounds__(256) void qkv_mfma(
    const float* __restrict__ x, const float* __restrict__ Wq,
    const float* __restrict__ Wk, const float* __restrict__ Wv,
    bf16* __restrict__ q, bf16* __restrict__ k, bf16* __restrict__ v)
{
    __shared__ bf16 A[64][72];    // [m][k], +8 pad
    __shared__ bf16 Bt[64][72];   // [n][k], +8 pad
    const int tid = threadIdx.x, w = tid >> 6, lane = tid & 63;
    const int l4 = lane & 15, quad = lane >> 4;
    const int m0 = blockIdx.x * 64;
    const int nb = blockIdx.y;                  // 0..17
    const int wi = nb / Hn, h = nb % Hn;
    const float* W = (wi == 0 ? Wq : (wi == 1 ? Wk : Wv)) + (size_t)h * Csz * Dh;
    bf16* outp = (wi == 0 ? q : (wi == 1 ? k : v));

    f32x4 acc[4] = {f32x4{0,0,0,0}, f32x4{0,0,0,0}, f32x4{0,0,0,0}, f32x4{0,0,0,0}};

    for (int kc = 0; kc < 6; ++kc) {
        // stage A: x rows m0..m0+63, cols kc*64..+64 (fp32 -> bf16)
        #pragma unroll
        for (int it = 0; it < 4; ++it) {
            int idx = it * 256 + tid;
            int r = idx >> 4, c4 = (idx & 15) * 4;
            float4 f = *(const float4*)&x[(size_t)(m0 + r) * Csz + kc * 64 + c4];
            union { bf16 b[4]; unsigned long long u; } pk;
            pk.b[0] = (bf16)f.x; pk.b[1] = (bf16)f.y;
            pk.b[2] = (bf16)f.z; pk.b[3] = (bf16)f.w;
            *(unsigned long long*)&A[r][c4] = pk.u;
        }
        // stage Bt (transpose): W[kc*64+kk][n], lane=kk -> conflict-free b16 writes
        #pragma unroll
        for (int it = 0; it < 4; ++it) {
            int kk = lane;
            int n4 = it * 16 + w * 4;
            float4 f = *(const float4*)&W[(size_t)(kc * 64 + kk) * Dh + n4];
            Bt[n4 + 0][kk] = (bf16)f.x; Bt[n4 + 1][kk] = (bf16)f.y;
            Bt[n4 + 2][kk] = (bf16)f.z; Bt[n4 + 3][kk] = (bf16)f.w;
        }
        __syncthreads();
        #pragma unroll
        for (int ks = 0; ks < 2; ++ks) {
            bf16x8 a = *(const bf16x8*)&A[w * 16 + l4][ks * 32 + quad * 8];
            #pragma unroll
            for (int nt = 0; nt < 4; ++nt) {
                bf16x8 b = *(const bf16x8*)&Bt[nt * 16 + l4][ks * 32 + quad * 8];
                acc[nt] = MFMA16(a, b, acc[nt]);
            }
        }
        __syncthreads();
    }
    // epilogue: out [B,H,T,D] bf16
    #pragma unroll
    for (int nt = 0; nt < 4; ++nt)
        #pragma unroll
        for (int r = 0; r < 4; ++r) {
            int m = m0 + w * 16 + quad * 4 + r;
            int b = m >> 8, t = m & 255;
            outp[(((size_t)(b * Hn + h)) * Tsz + t) * Dh + nt * 16 + l4] = (bf16)acc[nt][r];
        }
}

// ---------------- Flash attention, MFMA ----------------
// One block per (b, h, qtile of 64). Wave w owns q-rows [w*16, w*16+16).
// K-tile row-major LDS (B-frag of S-GEMM reads contiguous d), V-tile
// transposed LDS (B-frag of PV reads contiguous s). P goes C-layout regs ->
// wave-private LDS -> A-layout frags. Online softmax per C-row (quad*4+reg).
__global__ __launch_bounds__(256) void attn_mfma(
    const bf16* __restrict__ q, const bf16* __restrict__ k, const bf16* __restrict__ v,
    bf16* __restrict__ att)
{
    __shared__ bf16 Kl[64][72];
    __shared__ bf16 Vt[64][72];      // [d][s]
    __shared__ bf16 Pl[4][16][72];   // per-wave [qrow][s]
    const int tid = threadIdx.x, w = tid >> 6, lane = tid & 63;
    const int l4 = lane & 15, quad = lane >> 4;
    const int blk = blockIdx.x;
    const int bh = blk >> 2, qt = blk & 3;
    const int b = bh / Hn, h = bh % Hn;
    const bf16* qb = q + (size_t)bh * Tsz * Dh;
    const bf16* kb = k + (size_t)bh * Tsz * Dh;
    const bf16* vb = v + (size_t)bh * Tsz * Dh;

    // Q A-frags from global (wave-private rows, 16B aligned)
    const int trow = qt * 64 + w * 16 + l4;
    const bf16x8 qa0 = *(const bf16x8*)&qb[trow * Dh + quad * 8];
    const bf16x8 qa1 = *(const bf16x8*)&qb[trow * Dh + 32 + quad * 8];

    f32x4 o[4] = {f32x4{0,0,0,0}, f32x4{0,0,0,0}, f32x4{0,0,0,0}, f32x4{0,0,0,0}};
    float mrun[4] = {-3.0e38f, -3.0e38f, -3.0e38f, -3.0e38f};
    float lrun[4] = {0.f, 0.f, 0.f, 0.f};

    for (int kt = 0; kt <= qt; ++kt) {
        // stage K-tile row-major (coalesced b128 in+out, 2-way-free banks)
        #pragma unroll
        for (int it = 0; it < 2; ++it) {
            int idx = it * 256 + tid;
            int s = idx >> 3, d8 = (idx & 7) * 8;
            *(bf16x8*)&Kl[s][d8] = *(const bf16x8*)&kb[(kt * 64 + s) * Dh + d8];
        }
        // stage V-tile transposed: lane=s -> conflict-free b16 writes
        #pragma unroll
        for (int it = 0; it < 2; ++it) {
            int idx = it * 256 + tid;
            int s = idx & 63, d8 = (idx >> 6) * 8;
            bf16x8 vv = *(const bf16x8*)&vb[(kt * 64 + s) * Dh + d8];
            #pragma unroll
            for (int j = 0; j < 8; ++j) Vt[d8 + j][s] = vv[j];
        }
        __syncthreads();

        // S = Q.K^T  (16x16 C-tiles, nt = s-subtile)
        f32x4 sc[4] = {f32x4{0,0,0,0}, f32x4{0,0,0,0}, f32x4{0,0,0,0}, f32x4{0,0,0,0}};
        #pragma unroll
        for (int nt = 0; nt < 4; ++nt) {
            bf16x8 b0 = *(const bf16x8*)&Kl[nt * 16 + l4][quad * 8];
            bf16x8 b1 = *(const bf16x8*)&Kl[nt * 16 + l4][32 + quad * 8];
            sc[nt] = MFMA16(qa0, b0, sc[nt]);
            sc[nt] = MFMA16(qa1, b1, sc[nt]);
        }

        // scale + causal mask + online softmax (row = quad*4+r, col = lane&15)
        float mnew[4], alpha[4];
        #pragma unroll
        for (int r = 0; r < 4; ++r) {
            int tg = qt * 64 + w * 16 + quad * 4 + r;
            float mx = mrun[r];
            #pragma unroll
            for (int nt = 0; nt < 4; ++nt) {
                float sv = sc[nt][r] * 0.125f;
                int sg = kt * 64 + nt * 16 + l4;
                if (sg > tg) sv = -1.0e30f;
                sc[nt][r] = sv;
                mx = fmaxf(mx, sv);
            }
            mx = redmax16(mx);
            mnew[r] = mx;
            alpha[r] = __expf(mrun[r] - mx);
            mrun[r] = mx;
        }
        #pragma unroll
        for (int r = 0; r < 4; ++r) {
            float sm = 0.f;
            #pragma unroll
            for (int nt = 0; nt < 4; ++nt) {
                float e = __expf(sc[nt][r] - mnew[r]);
                sc[nt][r] = e;
                sm += e;
            }
            sm = redsum16(sm);
            lrun[r] = lrun[r] * alpha[r] + sm;
        }
        #pragma unroll
        for (int nt = 0; nt < 4; ++nt)
            #pragma unroll
            for (int r = 0; r < 4; ++r) o[nt][r] *= alpha[r];

        // P: C-layout regs -> wave-private LDS (hardware keeps per-wave DS order)
        #pragma unroll
        for (int nt = 0; nt < 4; ++nt)
            #pragma unroll
            for (int r = 0; r < 4; ++r)
                Pl[w][quad * 4 + r][nt * 16 + l4] = (bf16)sc[nt][r];

        // PV: A = P (A-layout read), B = Vt
        bf16x8 pa0 = *(const bf16x8*)&Pl[w][l4][quad * 8];
        bf16x8 pa1 = *(const bf16x8*)&Pl[w][l4][32 + quad * 8];
        #pragma unroll
        for (int nt = 0; nt < 4; ++nt) {
            bf16x8 vb0 = *(const bf16x8*)&Vt[nt * 16 + l4][quad * 8];
            bf16x8 vb1 = *(const bf16x8*)&Vt[nt * 16 + l4][32 + quad * 8];
            o[nt] = MFMA16(pa0, vb0, o[nt]);
            o[nt] = MFMA16(pa1, vb1, o[nt]);
        }
        __syncthreads();   // protect K/Vt restage
    }

    // epilogue: att [B,T,C] bf16, col = h*64 + d
    #pragma unroll
    for (int r = 0; r < 4; ++r) {
        float inv = 1.f / lrun[r];
        int tg = qt * 64 + w * 16 + quad * 4 + r;
        #pragma unroll
        for (int nt = 0; nt < 4; ++nt)
            att[((size_t)(b * Tsz + tg)) * Csz + h * Dh + nt * 16 + l4] =
                (bf16)(o[nt][r] * inv);
    }
}

// ---------------- Output projection, MFMA ----------------
// out[m,n] = att[m,:] . Wp[:,n] + bias[n].  Grid (1024, 6). A already bf16.
__global__ __launch_bounds__(256) void proj_mfma(
    const bf16* __restrict__ att, const float* __restrict__ Wp,
    const float* __restrict__ bias, float* __restrict__ out)
{
    __shared__ bf16 A[64][72];
    __shared__ bf16 Bt[64][72];
    const int tid = threadIdx.x, w = tid >> 6, lane = tid & 63;
    const int l4 = lane & 15, quad = lane >> 4;
    const int m0 = blockIdx.x * 64;
    const int n0 = blockIdx.y * 64;

    f32x4 acc[4] = {f32x4{0,0,0,0}, f32x4{0,0,0,0}, f32x4{0,0,0,0}, f32x4{0,0,0,0}};

    for (int kc = 0; kc < 6; ++kc) {
        #pragma unroll
        for (int it = 0; it < 2; ++it) {
            int idx = it * 256 + tid;
            int r = idx >> 3, c8 = (idx & 7) * 8;
            *(bf16x8*)&A[r][c8] = *(const bf16x8*)&att[(size_t)(m0 + r) * Csz + kc * 64 + c8];
        }
        #pragma unroll
        for (int it = 0; it < 4; ++it) {
            int kk = lane;
            int n4 = it * 16 + w * 4;
            float4 f = *(const float4*)&Wp[(size_t)(kc * 64 + kk) * Csz + n0 + n4];
            Bt[n4 + 0][kk] = (bf16)f.x; Bt[n4 + 1][kk] = (bf16)f.y;
            Bt[n4 + 2][kk] = (bf16)f.z; Bt[n4 + 3][kk] = (bf16)f.w;
        }
        __syncthreads();
        #pragma unroll
        for (int ks = 0; ks < 2; ++ks) {
            bf16x8 a = *(const bf16x8*)&A[w * 16 + l4][ks * 32 + quad * 8];
            #pragma unroll
            for (int nt = 0; nt < 4; ++nt) {
                bf16x8 b = *(const bf16x8*)&Bt[nt * 16 + l4][ks * 32 + quad * 8];
                acc[nt] = MFMA16(a, b, acc[nt]);
            }
        }
        __syncthreads();
    }
    #pragma unroll
    for (int nt = 0; nt < 4; ++nt) {
        float bv = bias[n0 + nt * 16 + l4];
        #pragma unroll
        for (int r = 0; r < 4; ++r) {
            int m = m0 + w * 16 + quad * 4 + r;
            out[(size_t)m * Csz + n0 + nt * 16 + l4] = acc[nt][r] + bv;
        }
    }
}

extern "C" void kernel_launch(void* const* d_in, const int* in_sizes, int n_in,
                              void* d_out, int out_size, void* d_ws, size_t ws_size,
                              hipStream_t stream)
{
    const float* x  = (const float*)d_in[0];
    const float* Wq = (const float*)d_in[1];
    const float* Wk = (const float*)d_in[2];
    const float* Wv = (const float*)d_in[3];
    const float* Wp = (const float*)d_in[4];
    const float* bp = (const float*)d_in[5];
    float* out = (float*)d_out;

    const size_t npe = (size_t)Bsz * Hn * Tsz * Dh;   // 25,165,824 elems
    bf16* q   = (bf16*)d_ws;      // [B,H,T,D]
    bf16* kk  = q  + npe;
    bf16* v   = kk + npe;
    bf16* att = v  + npe;         // [B,T,C]

    qkv_mfma<<<dim3(Bsz * Tsz / 64, 18), 256, 0, stream>>>(x, Wq, Wk, Wv, q, kk, v);
    attn_mfma<<<Bsz * Hn * 4, 256, 0, stream>>>(q, kk, v, att);
    proj_mfma<<<dim3(Bsz * Tsz / 64, Csz / 64), 256, 0, stream>>>(att, Wp, bp, out);
}

// Round 4
// 433.788 us; speedup vs baseline: 6.6363x; 1.5388x over previous
//
#include <hip/hip_runtime.h>
#include <hip/hip_bf16.h>

typedef __bf16 bf16;
typedef unsigned int u32;
typedef __attribute__((ext_vector_type(8))) __bf16 bf16x8;
typedef __attribute__((ext_vector_type(4))) float f32x4;

#define Bsz 256
#define Tsz 256
#define Csz 384
#define Hn  6
#define Dh  64
#define NQKV 1152   // 3 mats * 6 heads * 64

#define MFMA16(a, b, c) __builtin_amdgcn_mfma_f32_16x16x32_bf16(a, b, c, 0, 0, 0)

typedef __attribute__((address_space(3))) u32 lds_u32;
typedef __attribute__((address_space(1))) const u32 gbl_u32;
__device__ __forceinline__ void gl2lds16(const void* g, void* l) {
    // async global->LDS, 16B/lane; LDS dest = wave-uniform base + lane*16
    __builtin_amdgcn_global_load_lds((gbl_u32*)g, (lds_u32*)l, 16, 0, 0);
}

__device__ __forceinline__ float redmax16(float x) {
    x = fmaxf(x, __shfl_xor(x, 1));
    x = fmaxf(x, __shfl_xor(x, 2));
    x = fmaxf(x, __shfl_xor(x, 4));
    x = fmaxf(x, __shfl_xor(x, 8));
    return x;
}
__device__ __forceinline__ float redsum16(float x) {
    x += __shfl_xor(x, 1);
    x += __shfl_xor(x, 2);
    x += __shfl_xor(x, 4);
    x += __shfl_xor(x, 8);
    return x;
}

// ---------------- x: fp32 -> bf16 ----------------
__global__ __launch_bounds__(256) void convert_x(
    const float* __restrict__ x, bf16* __restrict__ xb)
{
    size_t i = ((size_t)blockIdx.x * 256 + threadIdx.x) * 8;
    float4 f0 = *(const float4*)&x[i];
    float4 f1 = *(const float4*)&x[i + 4];
    bf16x8 o;
    o[0] = (bf16)f0.x; o[1] = (bf16)f0.y; o[2] = (bf16)f0.z; o[3] = (bf16)f0.w;
    o[4] = (bf16)f1.x; o[5] = (bf16)f1.y; o[6] = (bf16)f1.z; o[7] = (bf16)f1.w;
    *(bf16x8*)&xb[i] = o;
}

// ---------------- weights: fp32 -> bf16, B^T [n][k] layout ----------------
// Btqkv[n][k], n = wi*384 + h*64 + d, k = c. Bpt[n][k] = Wp[k][n]. Tiny (2.4MB).
__global__ __launch_bounds__(384) void prep_w(
    const float* __restrict__ Wq, const float* __restrict__ Wk,
    const float* __restrict__ Wv, const float* __restrict__ Wp,
    bf16* __restrict__ Btqkv, bf16* __restrict__ Bpt)
{
    const int n = blockIdx.x, k = threadIdx.x;
    if (n < NQKV) {
        int wi = n / Csz, rem = n - wi * Csz, h = rem >> 6, d = rem & 63;
        const float* W = wi == 0 ? Wq : (wi == 1 ? Wk : Wv);
        Btqkv[(size_t)n * Csz + k] = (bf16)W[((size_t)h * Csz + k) * Dh + d];
    } else {
        int n2 = n - NQKV;
        Bpt[(size_t)n2 * Csz + k] = (bf16)Wp[(size_t)k * Csz + n2];
    }
}

// ---------------- QKV as one 65536x1152x384 GEMM (m97 structure) ----------------
// 128x128 tile, BK=64, global_load_lds width16, 2-barrier K-loop.
// Waves 2x2 over the tile; each wave 64x64 = 4x4 16x16 subtiles, 32 MFMA/iter.
// Epilogue scatters n -> (wi, h, d) into q/k/v [B,H,T,D] bf16.
__global__ __launch_bounds__(256) void qkv_gemm(
    const bf16* __restrict__ A, const bf16* __restrict__ Bt,
    bf16* __restrict__ q, bf16* __restrict__ k, bf16* __restrict__ v)
{
    __shared__ bf16 As[128][64];
    __shared__ bf16 Bs[128][64];
    const int tid = threadIdx.x, w = tid >> 6, lane = tid & 63;
    const int l4 = lane & 15, quad = lane >> 4;
    const int wm = w & 1, wn = w >> 1;
    const int m0 = blockIdx.x * 128, n0 = blockIdx.y * 128;
    const int srow = lane >> 3;          // 0..7 within an issue's 8 rows
    const int skk  = (lane & 7) * 8;     // k-elem offset (16B chunk)

    f32x4 acc[4][4] = {};

    for (int kc = 0; kc < Csz / 64; ++kc) {
        #pragma unroll
        for (int i = 0; i < 4; ++i) {
            int r = (w * 4 + i) * 8 + srow;
            gl2lds16(&A [(size_t)(m0 + r) * Csz + kc * 64 + skk],
                     (char*)&As[0][0] + (w * 4 + i) * 1024);
            gl2lds16(&Bt[(size_t)(n0 + r) * Csz + kc * 64 + skk],
                     (char*)&Bs[0][0] + (w * 4 + i) * 1024);
        }
        __syncthreads();
        #pragma unroll
        for (int ks = 0; ks < 2; ++ks) {
            bf16x8 af[4], bfr[4];
            #pragma unroll
            for (int mt = 0; mt < 4; ++mt)
                af[mt] = *(const bf16x8*)&As[wm * 64 + mt * 16 + l4][ks * 32 + quad * 8];
            #pragma unroll
            for (int nt = 0; nt < 4; ++nt)
                bfr[nt] = *(const bf16x8*)&Bs[wn * 64 + nt * 16 + l4][ks * 32 + quad * 8];
            #pragma unroll
            for (int mt = 0; mt < 4; ++mt)
                #pragma unroll
                for (int nt = 0; nt < 4; ++nt)
                    acc[mt][nt] = MFMA16(af[mt], bfr[nt], acc[mt][nt]);
        }
        __syncthreads();
    }

    #pragma unroll
    for (int nt = 0; nt < 4; ++nt) {
        int n = n0 + wn * 64 + nt * 16 + l4;
        int wi = n / Csz, rem = n - wi * Csz;
        int h = rem >> 6, d = rem & 63;
        bf16* outp = wi == 0 ? q : (wi == 1 ? k : v);
        #pragma unroll
        for (int mt = 0; mt < 4; ++mt)
            #pragma unroll
            for (int r = 0; r < 4; ++r) {
                int m = m0 + wm * 64 + mt * 16 + quad * 4 + r;
                int b = m >> 8, t = m & 255;
                outp[(((size_t)(b * Hn + h)) * Tsz + t) * Dh + d] = (bf16)acc[mt][nt][r];
            }
    }
}

// ---------------- Flash attention, MFMA (exp2-domain softmax) ----------------
__global__ __launch_bounds__(256) void attn_mfma(
    const bf16* __restrict__ q, const bf16* __restrict__ k, const bf16* __restrict__ v,
    bf16* __restrict__ att)
{
    __shared__ bf16 Kl[64][72];
    __shared__ bf16 Vt[64][72];      // [d][s]
    __shared__ bf16 Pl[4][16][72];   // per-wave [qrow][s]
    const float SCL = 0.18033688f;   // 0.125 * log2(e)
    const int tid = threadIdx.x, w = tid >> 6, lane = tid & 63;
    const int l4 = lane & 15, quad = lane >> 4;
    const int blk = blockIdx.x;
    const int bh = blk >> 2, qt = blk & 3;
    const int b = bh / Hn, h = bh % Hn;
    const bf16* qb = q + (size_t)bh * Tsz * Dh;
    const bf16* kb = k + (size_t)bh * Tsz * Dh;
    const bf16* vb = v + (size_t)bh * Tsz * Dh;

    const int trow = qt * 64 + w * 16 + l4;
    const bf16x8 qa0 = *(const bf16x8*)&qb[trow * Dh + quad * 8];
    const bf16x8 qa1 = *(const bf16x8*)&qb[trow * Dh + 32 + quad * 8];

    f32x4 o[4] = {f32x4{0,0,0,0}, f32x4{0,0,0,0}, f32x4{0,0,0,0}, f32x4{0,0,0,0}};
    float mrun[4] = {-3.0e38f, -3.0e38f, -3.0e38f, -3.0e38f};
    float lrun[4] = {0.f, 0.f, 0.f, 0.f};

    for (int kt = 0; kt <= qt; ++kt) {
        #pragma unroll
        for (int it = 0; it < 2; ++it) {
            int idx = it * 256 + tid;
            int s = idx >> 3, d8 = (idx & 7) * 8;
            *(bf16x8*)&Kl[s][d8] = *(const bf16x8*)&kb[(kt * 64 + s) * Dh + d8];
        }
        #pragma unroll
        for (int it = 0; it < 2; ++it) {
            int idx = it * 256 + tid;
            int s = idx & 63, d8 = (idx >> 6) * 8;
            bf16x8 vv = *(const bf16x8*)&vb[(kt * 64 + s) * Dh + d8];
            #pragma unroll
            for (int j = 0; j < 8; ++j) Vt[d8 + j][s] = vv[j];
        }
        __syncthreads();

        f32x4 sc[4] = {f32x4{0,0,0,0}, f32x4{0,0,0,0}, f32x4{0,0,0,0}, f32x4{0,0,0,0}};
        #pragma unroll
        for (int nt = 0; nt < 4; ++nt) {
            bf16x8 b0 = *(const bf16x8*)&Kl[nt * 16 + l4][quad * 8];
            bf16x8 b1 = *(const bf16x8*)&Kl[nt * 16 + l4][32 + quad * 8];
            sc[nt] = MFMA16(qa0, b0, sc[nt]);
            sc[nt] = MFMA16(qa1, b1, sc[nt]);
        }

        float mnew[4], alpha[4];
        #pragma unroll
        for (int r = 0; r < 4; ++r) {
            int tg = qt * 64 + w * 16 + quad * 4 + r;
            float mx = mrun[r];
            #pragma unroll
            for (int nt = 0; nt < 4; ++nt) {
                float sv = sc[nt][r] * SCL;        // log2-domain
                int sg = kt * 64 + nt * 16 + l4;
                if (sg > tg) sv = -1.0e30f;
                sc[nt][r] = sv;
                mx = fmaxf(mx, sv);
            }
            mx = redmax16(mx);
            mnew[r] = mx;
            alpha[r] = __builtin_amdgcn_exp2f(mrun[r] - mx);
            mrun[r] = mx;
        }
        #pragma unroll
        for (int r = 0; r < 4; ++r) {
            float sm = 0.f;
            #pragma unroll
            for (int nt = 0; nt < 4; ++nt) {
                float e = __builtin_amdgcn_exp2f(sc[nt][r] - mnew[r]);
                sc[nt][r] = e;
                sm += e;
            }
            sm = redsum16(sm);
            lrun[r] = lrun[r] * alpha[r] + sm;
        }
        #pragma unroll
        for (int nt = 0; nt < 4; ++nt)
            #pragma unroll
            for (int r = 0; r < 4; ++r) o[nt][r] *= alpha[r];

        #pragma unroll
        for (int nt = 0; nt < 4; ++nt)
            #pragma unroll
            for (int r = 0; r < 4; ++r)
                Pl[w][quad * 4 + r][nt * 16 + l4] = (bf16)sc[nt][r];

        bf16x8 pa0 = *(const bf16x8*)&Pl[w][l4][quad * 8];
        bf16x8 pa1 = *(const bf16x8*)&Pl[w][l4][32 + quad * 8];
        #pragma unroll
        for (int nt = 0; nt < 4; ++nt) {
            bf16x8 vb0 = *(const bf16x8*)&Vt[nt * 16 + l4][quad * 8];
            bf16x8 vb1 = *(const bf16x8*)&Vt[nt * 16 + l4][32 + quad * 8];
            o[nt] = MFMA16(pa0, vb0, o[nt]);
            o[nt] = MFMA16(pa1, vb1, o[nt]);
        }
        __syncthreads();
    }

    #pragma unroll
    for (int r = 0; r < 4; ++r) {
        float inv = 1.f / lrun[r];
        int tg = qt * 64 + w * 16 + quad * 4 + r;
        #pragma unroll
        for (int nt = 0; nt < 4; ++nt)
            att[((size_t)(b * Tsz + tg)) * Csz + h * Dh + nt * 16 + l4] =
                (bf16)(o[nt][r] * inv);
    }
}

// ---------------- Output projection as 65536x384x384 GEMM ----------------
__global__ __launch_bounds__(256) void proj_gemm(
    const bf16* __restrict__ A, const bf16* __restrict__ Bt,
    const float* __restrict__ bias, float* __restrict__ out)
{
    __shared__ bf16 As[128][64];
    __shared__ bf16 Bs[128][64];
    const int tid = threadIdx.x, w = tid >> 6, lane = tid & 63;
    const int l4 = lane & 15, quad = lane >> 4;
    const int wm = w & 1, wn = w >> 1;
    const int m0 = blockIdx.x * 128, n0 = blockIdx.y * 128;
    const int srow = lane >> 3;
    const int skk  = (lane & 7) * 8;

    f32x4 acc[4][4] = {};

    for (int kc = 0; kc < Csz / 64; ++kc) {
        #pragma unroll
        for (int i = 0; i < 4; ++i) {
            int r = (w * 4 + i) * 8 + srow;
            gl2lds16(&A [(size_t)(m0 + r) * Csz + kc * 64 + skk],
                     (char*)&As[0][0] + (w * 4 + i) * 1024);
            gl2lds16(&Bt[(size_t)(n0 + r) * Csz + kc * 64 + skk],
                     (char*)&Bs[0][0] + (w * 4 + i) * 1024);
        }
        __syncthreads();
        #pragma unroll
        for (int ks = 0; ks < 2; ++ks) {
            bf16x8 af[4], bfr[4];
            #pragma unroll
            for (int mt = 0; mt < 4; ++mt)
                af[mt] = *(const bf16x8*)&As[wm * 64 + mt * 16 + l4][ks * 32 + quad * 8];
            #pragma unroll
            for (int nt = 0; nt < 4; ++nt)
                bfr[nt] = *(const bf16x8*)&Bs[wn * 64 + nt * 16 + l4][ks * 32 + quad * 8];
            #pragma unroll
            for (int mt = 0; mt < 4; ++mt)
                #pragma unroll
                for (int nt = 0; nt < 4; ++nt)
                    acc[mt][nt] = MFMA16(af[mt], bfr[nt], acc[mt][nt]);
        }
        __syncthreads();
    }

    #pragma unroll
    for (int nt = 0; nt < 4; ++nt) {
        int n = n0 + wn * 64 + nt * 16 + l4;
        float bv = bias[n];
        #pragma unroll
        for (int mt = 0; mt < 4; ++mt)
            #pragma unroll
            for (int r = 0; r < 4; ++r) {
                int m = m0 + wm * 64 + mt * 16 + quad * 4 + r;
                out[(size_t)m * Csz + n] = acc[mt][nt][r] + bv;
            }
    }
}

extern "C" void kernel_launch(void* const* d_in, const int* in_sizes, int n_in,
                              void* d_out, int out_size, void* d_ws, size_t ws_size,
                              hipStream_t stream)
{
    const float* x  = (const float*)d_in[0];
    const float* Wq = (const float*)d_in[1];
    const float* Wk = (const float*)d_in[2];
    const float* Wv = (const float*)d_in[3];
    const float* Wp = (const float*)d_in[4];
    const float* bp = (const float*)d_in[5];
    float* out = (float*)d_out;

    const size_t npe = (size_t)Bsz * Tsz * Csz;   // 25,165,824 elems
    bf16* xb    = (bf16*)d_ws;          // [65536,384]; reused as att after qkv
    bf16* att   = xb;                   // alias: xb dead once qkv_gemm completes
    bf16* q     = xb + npe;             // [B,H,T,D]
    bf16* k     = q  + npe;
    bf16* v     = k  + npe;
    bf16* Btqkv = v  + npe;             // [1152,384]
    bf16* Bpt   = Btqkv + (size_t)NQKV * Csz;   // [384,384]

    convert_x<<<npe / 2048, 256, 0, stream>>>(x, xb);
    prep_w<<<NQKV + Csz, 384, 0, stream>>>(Wq, Wk, Wv, Wp, Btqkv, Bpt);
    qkv_gemm<<<dim3(Bsz * Tsz / 128, NQKV / 128), 256, 0, stream>>>(xb, Btqkv, q, k, v);
    attn_mfma<<<Bsz * Hn * 4, 256, 0, stream>>>(q, k, v, att);
    proj_gemm<<<dim3(Bsz * Tsz / 128, Csz / 128), 256, 0, stream>>>(att, Bpt, bp, out);
}